// Round 1
// baseline (12626.217 us; speedup 1.0000x reference)
//
#include <hip/hip_runtime.h>

#define Bn 256
#define Tn 512
#define Fn 128
#define Un 512
#define XFn 129      // F + 1 (interval)
#define BM 16        // batch rows per group
#define NC 32        // output cols per WG per gate
#define GC 16        // WGs per group (512 / 32)
#define NG 16        // groups (256 / 16)
#define KS 648       // LDS A row stride in bf16 elements (padded; 1296 B, 16B-aligned, 2-way banks)
#define KT 20        // K tiles: 640 / 32

typedef __attribute__((ext_vector_type(8))) short short8;
typedef __attribute__((ext_vector_type(4))) float floatx4;

__device__ __forceinline__ unsigned short f2bf(float f) {
  unsigned u = __float_as_uint(f);
  u += 0x7fffu + ((u >> 16) & 1u);            // RNE
  return (unsigned short)(u >> 16);
}
__device__ __forceinline__ float bf2f(unsigned short s) {
  return __uint_as_float(((unsigned)s) << 16);
}

// Monotonic-counter barrier among the GC workgroups of one group.
// Correct under cross-XCD L2 non-coherence: release fence before arrive,
// acquire fence after the spin (cache-wide ops cover the whole CU/XCD).
__device__ __forceinline__ void group_barrier(unsigned* cnt, unsigned target) {
  __syncthreads();                             // drains all waves' vmem (compiler emits vmcnt(0))
  if (threadIdx.x == 0) {
    __threadfence();                           // release (agent scope)
    __hip_atomic_fetch_add(cnt, 1u, __ATOMIC_RELAXED, __HIP_MEMORY_SCOPE_AGENT);
    while (__hip_atomic_load(cnt, __ATOMIC_RELAXED, __HIP_MEMORY_SCOPE_AGENT) < target) {
      __builtin_amdgcn_s_sleep(1);
    }
    __threadfence();                           // acquire
  }
  __syncthreads();
}

__global__ void zero_counters(unsigned* c) { c[threadIdx.x] = 0u; }

__global__ __launch_bounds__(256, 1)
void gru_kernel(const float* __restrict__ inp, const float* __restrict__ h0,
                const float* __restrict__ wz, const float* __restrict__ uz, const float* __restrict__ bz_,
                const float* __restrict__ wr, const float* __restrict__ ur, const float* __restrict__ br_,
                const float* __restrict__ wh, const float* __restrict__ uh, const float* __restrict__ bh_,
                const float* __restrict__ wint_, const float* __restrict__ bint_,
                float* __restrict__ out,
                unsigned short* __restrict__ h_buf, unsigned short* __restrict__ r_buf,
                unsigned* __restrict__ counters)
{
  __shared__ short Alds[16 * KS];   // A = [x (k=0..127) | h or h*r (k=128..639)], row m = batch row
  __shared__ float ivals[16];       // interval per batch row

  const int tid  = threadIdx.x;
  const int wave = tid >> 6;
  const int lane = tid & 63;
  const int ln   = lane & 15;
  const int quad = lane >> 4;
  const int g    = blockIdx.x & 15;   // group: members stride 16 apart -> same XCD under %8 round-robin
  const int wg   = blockIdx.x >> 4;   // N-slice id 0..15

  unsigned* cnt = counters + g * 16;  // one 64B line per group

  // ---- persistent register-resident B fragments (weights) ----
  // phase1: waves 0,1 -> z-slice cols; waves 2,3 -> r-slice cols
  const float* gw1 = (wave < 2) ? wz : wr;
  const float* gu1 = (wave < 2) ? uz : ur;
  const int ncol1 = wg * NC + (wave & 1) * 16 + ln;   // global U-col for this lane, gate 1
  short8 bf1[KT];
  #pragma unroll
  for (int kk = 0; kk < KT; ++kk) {
    short8 v;
    #pragma unroll
    for (int j = 0; j < 8; ++j) {
      int k = kk * 32 + quad * 8 + j;
      float w = (k < Fn) ? gw1[k * Un + ncol1] : gu1[(k - Fn) * Un + ncol1];
      v[j] = (short)f2bf(w);
    }
    bf1[kk] = v;
  }
  // phase2 (waves 0,1 only): w_h/u_h slice, same cols as z
  const int ncol2 = wg * NC + wave * 16 + ln;          // valid for wave<2
  short8 bf2[KT];
  if (wave < 2) {
    #pragma unroll
    for (int kk = 0; kk < KT; ++kk) {
      short8 v;
      #pragma unroll
      for (int j = 0; j < 8; ++j) {
        int k = kk * 32 + quad * 8 + j;
        float w = (k < Fn) ? wh[k * Un + ncol2] : uh[(k - Fn) * Un + ncol2];
        v[j] = (short)f2bf(w);
      }
      bf2[kk] = v;
    }
  }

  const float bz = bz_[0], br = br_[0], bh = bh_[0], bint = bint_[0];
  const float wint = (wave < 2) ? wint_[ncol2] : 0.f;

  // fp32 own-slice h (for the z*h term), C/D layout: row = quad*4+i, col = ncol2
  float hold[4] = {0.f, 0.f, 0.f, 0.f};
  if (wave < 2) {
    #pragma unroll
    for (int i = 0; i < 4; ++i)
      hold[i] = h0[(size_t)(g * BM + quad * 4 + i) * Un + ncol2];
  }

  const int sm = tid >> 4;        // staging row 0..15
  const int sc = tid & 15;        // staging chunk

  for (int t = 0; t < Tn; ++t) {
    // ---- stage x(t) -> LDS (bf16) + interval ----
    {
      const float* xr = inp + ((size_t)(g * BM + sm) * Tn + t) * XFn + sc * 8;
      short8 xb;
      #pragma unroll
      for (int j = 0; j < 8; ++j) xb[j] = (short)f2bf(xr[j]);
      *(short8*)&Alds[sm * KS + sc * 8] = xb;
      if (tid < 16)
        ivals[tid] = inp[((size_t)(g * BM + tid) * Tn + t) * XFn + Fn];
    }
    // ---- stage h(t-1) -> LDS ----
    if (t == 0) {
      const float* hp = h0 + (size_t)(g * BM + sm) * Un + sc * 32;
      #pragma unroll
      for (int jj = 0; jj < 32; jj += 8) {
        short8 hb;
        #pragma unroll
        for (int q = 0; q < 8; ++q) hb[q] = (short)f2bf(hp[jj + q]);
        *(short8*)&Alds[sm * KS + Fn + sc * 32 + jj] = hb;
      }
    } else {
      const unsigned short* hp = h_buf + (size_t)(g * BM + sm) * Un + sc * 32;
      #pragma unroll
      for (int jj = 0; jj < 32; jj += 8)
        *(short8*)&Alds[sm * KS + Fn + sc * 32 + jj] = *(const short8*)&hp[jj];
    }
    __syncthreads();

    // ---- phase 1: zr_pre = [x|h] @ B1 ----
    floatx4 acc = {0.f, 0.f, 0.f, 0.f};
    {
      const short* ap = &Alds[ln * KS + quad * 8];
      #pragma unroll
      for (int kk = 0; kk < KT; ++kk) {
        short8 a = *(const short8*)(ap + kk * 32);
        acc = __builtin_amdgcn_mfma_f32_16x16x32_bf16(a, bf1[kk], acc, 0, 0, 0);
      }
    }
    float zf[4];
    if (wave < 2) {
      #pragma unroll
      for (int i = 0; i < 4; ++i) zf[i] = 1.f / (1.f + __expf(-(acc[i] + bz)));
    } else {
      #pragma unroll
      for (int i = 0; i < 4; ++i) {
        float r = 1.f / (1.f + __expf(-(acc[i] + br)));
        r_buf[(size_t)(g * BM + quad * 4 + i) * Un + ncol1] = f2bf(r);
      }
    }

    group_barrier(cnt, (unsigned)(GC * (2 * t + 1)));   // r published

    // ---- h-region := h .* r (in place, bf16) ----
    {
      const unsigned short* rp = r_buf + (size_t)(g * BM + sm) * Un + sc * 32;
      short* ap = &Alds[sm * KS + Fn + sc * 32];
      #pragma unroll
      for (int jj = 0; jj < 32; jj += 8) {
        short8 hv = *(short8*)(ap + jj);
        short8 rv = *(const short8*)&rp[jj];
        short8 o;
        #pragma unroll
        for (int q = 0; q < 8; ++q)
          o[q] = (short)f2bf(bf2f((unsigned short)hv[q]) * bf2f((unsigned short)rv[q]));
        *(short8*)(ap + jj) = o;
      }
    }
    __syncthreads();

    // ---- phase 2 (waves 0,1): hhat_pre = [x|h.*r] @ B2; epilogue; publish h ----
    if (wave < 2) {
      floatx4 acc2 = {0.f, 0.f, 0.f, 0.f};
      const short* ap = &Alds[ln * KS + quad * 8];
      #pragma unroll
      for (int kk = 0; kk < KT; ++kk) {
        short8 a = *(const short8*)(ap + kk * 32);
        acc2 = __builtin_amdgcn_mfma_f32_16x16x32_bf16(a, bf2[kk], acc2, 0, 0, 0);
      }
      #pragma unroll
      for (int i = 0; i < 4; ++i) {
        int m = quad * 4 + i;
        float hh  = 1.f - 2.f / (__expf(2.f * (acc2[i] + bh)) + 1.f);   // tanh
        float dec = __expf(-fmaxf(ivals[m] * wint + bint, 0.f));
        float hn  = dec * (zf[i] * hold[i] + (1.f - zf[i]) * hh);
        hold[i] = hn;
        out[((size_t)(g * BM + m) * Tn + t) * Un + ncol2] = hn;
        h_buf[(size_t)(g * BM + m) * Un + ncol2] = f2bf(hn);
      }
    }

    group_barrier(cnt, (unsigned)(GC * (2 * t + 2)));   // h published
  }
}

extern "C" void kernel_launch(void* const* d_in, const int* in_sizes, int n_in,
                              void* d_out, int out_size, void* d_ws, size_t ws_size,
                              hipStream_t stream) {
  const float* inp  = (const float*)d_in[0];
  const float* h0   = (const float*)d_in[1];
  const float* wz   = (const float*)d_in[2];
  const float* uz   = (const float*)d_in[3];
  const float* bz   = (const float*)d_in[4];
  const float* wr   = (const float*)d_in[5];
  const float* ur   = (const float*)d_in[6];
  const float* br   = (const float*)d_in[7];
  const float* wh   = (const float*)d_in[8];
  const float* uh   = (const float*)d_in[9];
  const float* bh   = (const float*)d_in[10];
  const float* wint = (const float*)d_in[11];
  const float* bint = (const float*)d_in[12];
  float* out = (float*)d_out;

  // ws layout: [0,1KB) barrier counters (16 groups x 64B) | r_buf 256KB | h_buf 256KB
  unsigned* counters   = (unsigned*)d_ws;
  unsigned short* r_buf = (unsigned short*)((char*)d_ws + 1024);
  unsigned short* h_buf = (unsigned short*)((char*)d_ws + 1024 + (size_t)Bn * Un * 2);

  hipLaunchKernelGGL(zero_counters, dim3(1), dim3(256), 0, stream, counters);

  void* args[] = {(void*)&inp, (void*)&h0, (void*)&wz, (void*)&uz, (void*)&bz,
                  (void*)&wr, (void*)&ur, (void*)&br, (void*)&wh, (void*)&uh,
                  (void*)&bh, (void*)&wint, (void*)&bint, (void*)&out,
                  (void*)&h_buf, (void*)&r_buf, (void*)&counters};
  hipError_t e = hipLaunchCooperativeKernel((void*)gru_kernel, dim3(NG * GC), dim3(256),
                                            args, 0, stream);
  if (e != hipSuccess) {
    // fallback: plain launch (256 blocks / 1 per CU are co-resident in practice)
    hipLaunchKernelGGL(gru_kernel, dim3(NG * GC), dim3(256), 0, stream,
                       inp, h0, wz, uz, bz, wr, ur, br, wh, uh, bh, wint, bint,
                       out, h_buf, r_buf, counters);
  }
}

// Round 2
// 3172.470 us; speedup vs baseline: 3.9799x; 3.9799x over previous
//
#include <hip/hip_runtime.h>

#define Bn 256
#define Tn 512
#define Fn 128
#define Un 512
#define XFn 129      // F + 1 (interval)
#define BM 16        // batch rows per group
#define GC 16        // WGs per group (512 cols / 32)
#define NG 16        // groups (256 rows / 16)
#define XS 136       // x row stride in shorts (272 B, 16B-aligned)
#define HS 520       // h row stride in shorts (1040 B, 16B-aligned)
#define KT 20        // K tiles: 640 / 32

typedef __attribute__((ext_vector_type(8))) short short8;
typedef __attribute__((ext_vector_type(4))) float floatx4;
typedef unsigned long long ull;

__device__ __forceinline__ unsigned short f2bf(float f) {
  unsigned u = __float_as_uint(f);
  u += 0x7fffu + ((u >> 16) & 1u);            // RNE
  return (unsigned short)(u >> 16);
}
__device__ __forceinline__ float bf2f(unsigned v) {       // low 16 bits
  return __uint_as_float((v & 0xffffu) << 16);
}

// Per-instruction coherent (sc0 sc1 -> MALL) accesses. No cache-wide
// maintenance is ever emitted for RELAXED+AGENT atomics.
__device__ __forceinline__ ull ldc8(const void* p) {
  return __hip_atomic_load((const ull*)p, __ATOMIC_RELAXED, __HIP_MEMORY_SCOPE_AGENT);
}
__device__ __forceinline__ void stc8(void* p, ull v) {
  __hip_atomic_store((ull*)p, v, __ATOMIC_RELAXED, __HIP_MEMORY_SCOPE_AGENT);
}
__device__ __forceinline__ ull pack4(float a, float b, float c, float d) {
  return (ull)f2bf(a) | ((ull)f2bf(b) << 16) | ((ull)f2bf(c) << 32) | ((ull)f2bf(d) << 48);
}

// Fence-free group barrier. Safe because: (1) __syncthreads drains vmcnt(0),
// so every lane's sc1 (coherence-point) store has been ACKed by MALL before
// thread 0 increments; (2) consumers re-read data with sc1 loads (no stale
// L1/L2 copies can exist -- all comm traffic bypasses those caches).
__device__ __forceinline__ void group_barrier(unsigned* cnt, unsigned target) {
  __syncthreads();
  if (threadIdx.x == 0) {
    __hip_atomic_fetch_add(cnt, 1u, __ATOMIC_RELAXED, __HIP_MEMORY_SCOPE_AGENT);
    while (__hip_atomic_load(cnt, __ATOMIC_RELAXED, __HIP_MEMORY_SCOPE_AGENT) < target)
      __builtin_amdgcn_s_sleep(1);
  }
  __syncthreads();
}

__global__ void zero_counters(unsigned* c) { c[threadIdx.x] = 0u; }

// Comm buffers are TRANSPOSED: buf_T[col][row], 16 rows (bf16) per col = 32 B.
// An MFMA output lane (col fixed, rows quad*4..+3) publishes one 8B store.

__global__ __launch_bounds__(256, 1)
void gru_kernel(const float* __restrict__ inp, const float* __restrict__ h0,
                const float* __restrict__ wz, const float* __restrict__ uz, const float* __restrict__ bz_,
                const float* __restrict__ wr, const float* __restrict__ ur, const float* __restrict__ br_,
                const float* __restrict__ wh, const float* __restrict__ uh, const float* __restrict__ bh_,
                const float* __restrict__ wint_, const float* __restrict__ bint_,
                float* __restrict__ out,
                unsigned short* __restrict__ h_buf, unsigned short* __restrict__ r_buf,
                unsigned* __restrict__ counters)
{
  __shared__ short Xlds[2][16 * XS];   // x(t) bf16, double-buffered
  __shared__ short Hlds[16 * HS];      // h(t-1), then h(t-1).*r in place
  __shared__ float ivals[2][16];

  const int tid  = threadIdx.x;
  const int wave = tid >> 6;
  const int lane = tid & 63;
  const int ln   = lane & 15;
  const int quad = lane >> 4;
  const int g    = blockIdx.x & 15;   // members stride 16 -> same XCD under %8 round-robin
  const int wg   = blockIdx.x >> 4;   // N-slice 0..15

  unsigned* cnt = counters + g * 16;
  unsigned short* rg = r_buf + (size_t)g * (Un * BM);   // [512 cols][16 rows]
  unsigned short* hg = h_buf + (size_t)g * (Un * BM);

  // ---- persistent register-resident weights ----
  const float* gw1 = (wave < 2) ? wz : wr;
  const float* gu1 = (wave < 2) ? uz : ur;
  const int ncol1 = wg * 32 + (wave & 1) * 16 + ln;     // gate-1 col (z for w0/1, r for w2/3)
  short8 bf1[KT];
  #pragma unroll
  for (int kk = 0; kk < KT; ++kk) {
    short8 v;
    #pragma unroll
    for (int j = 0; j < 8; ++j) {
      int k = kk * 32 + quad * 8 + j;
      float w = (k < Fn) ? gw1[k * Un + ncol1] : gu1[(k - Fn) * Un + ncol1];
      v[j] = (short)f2bf(w);
    }
    bf1[kk] = v;
  }
  const int ncol2 = wg * 32 + wave * 16 + ln;           // valid for wave<2 (== ncol1 there)
  short8 bf2[KT];
  if (wave < 2) {
    #pragma unroll
    for (int kk = 0; kk < KT; ++kk) {
      short8 v;
      #pragma unroll
      for (int j = 0; j < 8; ++j) {
        int k = kk * 32 + quad * 8 + j;
        float w = (k < Fn) ? wh[k * Un + ncol2] : uh[(k - Fn) * Un + ncol2];
        v[j] = (short)f2bf(w);
      }
      bf2[kk] = v;
    }
  }

  const float bz = bz_[0], br = br_[0], bh = bh_[0], bint = bint_[0];
  const float wint = (wave < 2) ? wint_[ncol2] : 0.f;

  float hold[4] = {0.f, 0.f, 0.f, 0.f};
  if (wave < 2) {
    #pragma unroll
    for (int i = 0; i < 4; ++i)
      hold[i] = h0[(size_t)(g * BM + quad * 4 + i) * Un + ncol2];
  }

  // ---- prologue: stage x(0), ivals[0], Hlds <- h0 ----
  {
    int row = tid >> 4, ch = tid & 15;
    const float* xr = inp + ((size_t)(g * BM + row) * Tn + 0) * XFn + ch * 8;
    short8 v;
    #pragma unroll
    for (int j = 0; j < 8; ++j) v[j] = (short)f2bf(xr[j]);
    *(short8*)&Xlds[0][row * XS + ch * 8] = v;
    if (tid < 16)
      ivals[0][tid] = inp[((size_t)(g * BM + tid) * Tn + 0) * XFn + Fn];
    const float* hp = h0 + (size_t)(g * BM + row) * Un + ch * 32;
    #pragma unroll
    for (int s = 0; s < 4; ++s) {
      short8 hv;
      #pragma unroll
      for (int j = 0; j < 8; ++j) hv[j] = (short)f2bf(hp[s * 8 + j]);
      *(short8*)&Hlds[row * HS + ch * 32 + s * 8] = hv;
    }
  }

  for (int t = 0; t < Tn; ++t) {
    const int buf = t & 1;

    // ---- stage h(t-1): h_buf_T (coherent) -> Hlds (transpose) ----
    if (t > 0) {
      const int c0 = tid * 2;
      ull ha[4], hb[4];
      #pragma unroll
      for (int q = 0; q < 4; ++q) ha[q] = ldc8(hg + (size_t)c0 * BM + q * 4);
      #pragma unroll
      for (int q = 0; q < 4; ++q) hb[q] = ldc8(hg + (size_t)(c0 + 1) * BM + q * 4);
      #pragma unroll
      for (int r = 0; r < 16; ++r) {
        unsigned lo = (unsigned)((ha[r >> 2] >> ((r & 3) * 16)) & 0xffffu);
        unsigned hi = (unsigned)((hb[r >> 2] >> ((r & 3) * 16)) & 0xffffu);
        *(unsigned*)&Hlds[r * HS + c0] = lo | (hi << 16);
      }
    }
    __syncthreads();

    // ---- phase 1: [x|h] @ [Wz;Uz | Wr;Ur], 2-way split acc chain ----
    floatx4 a0 = {0.f,0.f,0.f,0.f}, a1 = {0.f,0.f,0.f,0.f};
    {
      const short* xb = &Xlds[buf][ln * XS + quad * 8];
      const short* hb = &Hlds[ln * HS + quad * 8];
      #pragma unroll
      for (int kk = 0; kk < KT; ++kk) {
        const short* ap = (kk < 4) ? (xb + kk * 32) : (hb + (kk - 4) * 32);
        short8 a = *(const short8*)ap;
        if (kk & 1) a1 = __builtin_amdgcn_mfma_f32_16x16x32_bf16(a, bf1[kk], a1, 0, 0, 0);
        else        a0 = __builtin_amdgcn_mfma_f32_16x16x32_bf16(a, bf1[kk], a0, 0, 0, 0);
      }
    }
    float zf[4];
    {
      floatx4 acc = a0 + a1;
      if (wave < 2) {
        #pragma unroll
        for (int i = 0; i < 4; ++i) zf[i] = 1.f / (1.f + __expf(-(acc[i] + bz)));
      } else {
        float rv[4];
        #pragma unroll
        for (int i = 0; i < 4; ++i) rv[i] = 1.f / (1.f + __expf(-(acc[i] + br)));
        stc8(rg + (size_t)ncol1 * BM + quad * 4, pack4(rv[0], rv[1], rv[2], rv[3]));
      }
    }

    group_barrier(cnt, (unsigned)(GC * (2 * t + 1)));   // r published

    // ---- Hlds := Hlds .* r  (r from coherent r_buf_T) ----
    {
      const int c0 = tid * 2;
      ull ra[4], rb[4];
      #pragma unroll
      for (int q = 0; q < 4; ++q) ra[q] = ldc8(rg + (size_t)c0 * BM + q * 4);
      #pragma unroll
      for (int q = 0; q < 4; ++q) rb[q] = ldc8(rg + (size_t)(c0 + 1) * BM + q * 4);
      #pragma unroll
      for (int r = 0; r < 16; ++r) {
        unsigned hv = *(unsigned*)&Hlds[r * HS + c0];
        float p0 = bf2f(hv) * bf2f((unsigned)(ra[r >> 2] >> ((r & 3) * 16)));
        float p1 = bf2f(hv >> 16) * bf2f((unsigned)(rb[r >> 2] >> ((r & 3) * 16)));
        *(unsigned*)&Hlds[r * HS + c0] = (unsigned)f2bf(p0) | ((unsigned)f2bf(p1) << 16);
      }
    }
    __syncthreads();

    // ---- phase 2 (waves 0,1) + x(t+1) staging (waves 2,3) ----
    if (wave < 2) {
      floatx4 b0 = {0.f,0.f,0.f,0.f}, b1 = {0.f,0.f,0.f,0.f};
      const short* xb = &Xlds[buf][ln * XS + quad * 8];
      const short* hb = &Hlds[ln * HS + quad * 8];
      #pragma unroll
      for (int kk = 0; kk < KT; ++kk) {
        const short* ap = (kk < 4) ? (xb + kk * 32) : (hb + (kk - 4) * 32);
        short8 a = *(const short8*)ap;
        if (kk & 1) b1 = __builtin_amdgcn_mfma_f32_16x16x32_bf16(a, bf2[kk], b1, 0, 0, 0);
        else        b0 = __builtin_amdgcn_mfma_f32_16x16x32_bf16(a, bf2[kk], b0, 0, 0, 0);
      }
      floatx4 acc2 = b0 + b1;
      float hn[4];
      #pragma unroll
      for (int i = 0; i < 4; ++i) {
        int m = quad * 4 + i;
        float hh  = 1.f - 2.f / (__expf(2.f * (acc2[i] + bh)) + 1.f);
        float dec = __expf(-fmaxf(ivals[buf][m] * wint + bint, 0.f));
        float v   = dec * (zf[i] * hold[i] + (1.f - zf[i]) * hh);
        hold[i] = v; hn[i] = v;
        out[((size_t)(g * BM + m) * Tn + t) * Un + ncol2] = v;
      }
      stc8(hg + (size_t)ncol2 * BM + quad * 4, pack4(hn[0], hn[1], hn[2], hn[3]));
    } else if (t + 1 < Tn) {
      int id = tid - 128;               // 0..127
      int row = id >> 3, ch = id & 7;   // 16 shorts per thread
      const float* xr = inp + ((size_t)(g * BM + row) * Tn + (t + 1)) * XFn + ch * 16;
      short8 v0, v1;
      #pragma unroll
      for (int j = 0; j < 8; ++j) { v0[j] = (short)f2bf(xr[j]); v1[j] = (short)f2bf(xr[8 + j]); }
      *(short8*)&Xlds[buf ^ 1][row * XS + ch * 16]     = v0;
      *(short8*)&Xlds[buf ^ 1][row * XS + ch * 16 + 8] = v1;
      if (id < 16)
        ivals[buf ^ 1][id] = inp[((size_t)(g * BM + id) * Tn + (t + 1)) * XFn + Fn];
    }

    group_barrier(cnt, (unsigned)(GC * (2 * t + 2)));   // h published
  }
}

extern "C" void kernel_launch(void* const* d_in, const int* in_sizes, int n_in,
                              void* d_out, int out_size, void* d_ws, size_t ws_size,
                              hipStream_t stream) {
  const float* inp  = (const float*)d_in[0];
  const float* h0   = (const float*)d_in[1];
  const float* wz   = (const float*)d_in[2];
  const float* uz   = (const float*)d_in[3];
  const float* bz   = (const float*)d_in[4];
  const float* wr   = (const float*)d_in[5];
  const float* ur   = (const float*)d_in[6];
  const float* br   = (const float*)d_in[7];
  const float* wh   = (const float*)d_in[8];
  const float* uh   = (const float*)d_in[9];
  const float* bh   = (const float*)d_in[10];
  const float* wint = (const float*)d_in[11];
  const float* bint = (const float*)d_in[12];
  float* out = (float*)d_out;

  // ws: [0,1KB) barrier counters | r_buf_T 256KB | h_buf_T 256KB
  unsigned* counters    = (unsigned*)d_ws;
  unsigned short* r_buf = (unsigned short*)((char*)d_ws + 1024);
  unsigned short* h_buf = (unsigned short*)((char*)d_ws + 1024 + (size_t)Bn * Un * 2);

  hipLaunchKernelGGL(zero_counters, dim3(1), dim3(256), 0, stream, counters);

  void* args[] = {(void*)&inp, (void*)&h0, (void*)&wz, (void*)&uz, (void*)&bz,
                  (void*)&wr, (void*)&ur, (void*)&br, (void*)&wh, (void*)&uh,
                  (void*)&bh, (void*)&wint, (void*)&bint, (void*)&out,
                  (void*)&h_buf, (void*)&r_buf, (void*)&counters};
  hipError_t e = hipLaunchCooperativeKernel((void*)gru_kernel, dim3(NG * GC), dim3(256),
                                            args, 0, stream);
  if (e != hipSuccess) {
    hipLaunchKernelGGL(gru_kernel, dim3(NG * GC), dim3(256), 0, stream,
                       inp, h0, wz, uz, bz, wr, ur, br, wh, uh, bh, wint, bint,
                       out, h_buf, r_buf, counters);
  }
}